// Round 5
// baseline (174.683 us; speedup 1.0000x reference)
//
#include <hip/hip_runtime.h>
#include <hip/hip_cooperative_groups.h>
#include <math.h>

namespace cg = cooperative_groups;

#define LOG_SQRT_2PI 0.9189385332046727f
typedef float f32x4 __attribute__((ext_vector_type(4)));

// ---------------------------------------------------------------------------
// Per-row prior NLL (branchy expected-mu + 7-element gaussian NLL sum).
// ---------------------------------------------------------------------------
__device__ __forceinline__ float prior_row(const float* __restrict__ pred,
                                           const float* __restrict__ sigma,
                                           int b) {
    const float* p  = pred  + (size_t)b * 7;
    const float* sg = sigma + (size_t)b * 7;
    float O2 = p[0], N2 = p[1], H2 = p[2], CO2 = p[3];
    float H2O = p[4], CH4 = p[5], NH3 = p[6];

    float H = 2.f*H2 + 2.f*H2O + 3.f*NH3 + 4.f*CH4;
    float C = CO2 + CH4;
    float O = 2.f*O2 + 2.f*CO2 + H2O;
    float N = 2.f*N2 + NH3;

    float mu0=0.f, mu1=0.f, mu2=0.f, mu3=0.f, mu4=0.f, mu5=0.f, mu6=0.f;

    bool condA = (H > 2.f*O + 4.f*C);
    if (condA) {
        if (3.f*N < H - 2.f*O - 4.f*C) {
            float D = H - N - 2.f*C;                 // branch A1
            mu2 = (H - 2.f*O - 4.f*C - 3.f*N) / D;
            mu4 = (2.f*O) / D;
            mu5 = (2.f*C) / D;
            mu6 = (2.f*N) / D;
        } else {
            float D = H + 2.f*C + 3.f*N + 4.f*O;    // branch A2
            mu1 = (3.f*N + 4.f*C + 2.f*O - H) / D;
            mu4 = (6.f*O) / D;
            mu5 = (6.f*C) / D;
            mu6 = (2.f*H - 8.f*C - 4.f*O) / D;
        }
    } else if (2.f*O > H + 4.f*C) {
        float D = H + 2.f*O + 2.f*N;                // branch B
        mu0 = (2.f*O - H - 4.f*C) / D;
        mu1 = (2.f*N) / D;
        mu3 = (4.f*C) / D;
        mu4 = (2.f*H) / D;
    } else if (fabsf(H + C + O + N - 1.0f) < 1e-3f) {
        float D1 = H + 2.f*O + 2.f*N;               // branch C
        float D2 = 2.f*H + 4.f*O + 4.f*N;
        mu1 = (2.f*N) / D1;
        mu3 = (2.f*O + 4.f*C - H) / D2;
        mu4 = (H + 2.f*O - 4.f*C) / D1;
        mu5 = (H - 2.f*O + 4.f*C) / D2;
    }

    float mu[7] = {mu0, mu1, mu2, mu3, mu4, mu5, mu6};
    float s = 0.f;
    #pragma unroll
    for (int i = 0; i < 7; ++i) {
        float d = p[i] - mu[i];
        float sgi = sg[i];
        s += LOG_SQRT_2PI + logf(sgi) + d * d / (2.0f * sgi * sgi);
    }
    return s;
}

// ---------------------------------------------------------------------------
// Fused cooperative kernel. nb = grid size (co-resident).
// phase1: prior partials distributed across ALL blocks (scattered rows)
// phase2: stream rows blk, blk+nb, ... with the round-2 inner loop
// phase3: grid sync (fences ws)
// phase4: total prior + write out
// Requires: S == NITER*1024, ceil(B/nb) <= 32.
// ---------------------------------------------------------------------------
template <int NITER>
__global__ __launch_bounds__(256, 8) void fused_loss(
        const float* __restrict__ pred, const float* __restrict__ sigma,
        const float* __restrict__ yReal, const float* __restrict__ ySim,
        float* __restrict__ ws, float* __restrict__ out,
        int B, int S, float c_mse, float c_prior, int nb) {
    int blk  = blockIdx.x;
    int lane = threadIdx.x & 63, w = threadIdx.x >> 6;

    // ---- phase 1: prior partial for rows blk + nb*(tid + 256*j) ----
    float ps = 0.f;
    for (int b = blk + nb * threadIdx.x; b < B; b += nb * 256)
        ps += prior_row(pred, sigma, b);
    #pragma unroll
    for (int off = 32; off; off >>= 1) ps += __shfl_down(ps, off, 64);
    __shared__ float psh[4];
    if (lane == 0) psh[w] = ps;
    __syncthreads();
    if (threadIdx.x == 0) ws[blk] = psh[0] + psh[1] + psh[2] + psh[3];

    // ---- phase 2: stream this block's rows sequentially ----
    __shared__ float wsum[4][32];
    int nr = 0;
    for (int row = blk; row < B; row += nb, ++nr) {
        const f32x4* yr = (const f32x4*)(yReal + (size_t)row * S);
        const f32x4* ys = (const f32x4*)(ySim  + (size_t)row * S);
        float s = 0.f;
        #pragma unroll
        for (int k = 0; k < NITER; ++k) {
            int i = threadIdx.x + k * 256;
            f32x4 a = yr[i], c = ys[i];
            f32x4 d = a - c;
            s += d.x*d.x + d.y*d.y + d.z*d.z + d.w*d.w;
        }
        #pragma unroll
        for (int off = 32; off; off >>= 1) s += __shfl_down(s, off, 64);
        if (lane == 0) wsum[w][nr] = s;
    }

    // ---- phase 3: grid-wide sync (also a block barrier + device fence) ----
    cg::this_grid().sync();

    // ---- phase 4: total prior, then write outputs ----
    float u = 0.f;
    for (int i = threadIdx.x; i < nb; i += 256) u += ws[i];
    #pragma unroll
    for (int off = 32; off; off >>= 1) u += __shfl_down(u, off, 64);
    __shared__ float usum[4];
    if (lane == 0) usum[w] = u;
    __syncthreads();
    float total = (usum[0] + usum[1] + usum[2] + usum[3]) * c_prior;

    if (threadIdx.x < nr) {
        float ms = wsum[0][threadIdx.x] + wsum[1][threadIdx.x]
                 + wsum[2][threadIdx.x] + wsum[3][threadIdx.x];
        out[blk + nb * threadIdx.x] = ms * c_mse + total;
    }
}

// ---------------------------------------------------------------------------
// Fallback path (round-2 structure, proven 47.3 us).
// ---------------------------------------------------------------------------
__global__ __launch_bounds__(256) void prior_partials(
        const float* __restrict__ pred,
        const float* __restrict__ sigma,
        float* __restrict__ ws, int B, int pb) {
    float s = 0.0f;
    for (int b = blockIdx.x * 256 + threadIdx.x; b < B; b += pb * 256)
        s += prior_row(pred, sigma, b);
    #pragma unroll
    for (int off = 32; off > 0; off >>= 1) s += __shfl_down(s, off, 64);
    __shared__ float wsum[4];
    int lane = threadIdx.x & 63, w = threadIdx.x >> 6;
    if (lane == 0) wsum[w] = s;
    __syncthreads();
    if (threadIdx.x == 0) ws[blockIdx.x] = wsum[0] + wsum[1] + wsum[2] + wsum[3];
}

__global__ __launch_bounds__(256) void loss_kernel_g(
        const float* __restrict__ yReal,
        const float* __restrict__ ySim,
        const float* __restrict__ partials,
        float* __restrict__ out, int S, float c_mse, float c_prior, int pb) {
    int b = blockIdx.x;
    const float* yr = yReal + (size_t)b * S;
    const float* ys = ySim  + (size_t)b * S;

    float u = (threadIdx.x < pb) ? partials[threadIdx.x] * c_prior : 0.0f;

    float s = 0.0f;
    int n4 = S >> 2;
    const f32x4* yr4 = (const f32x4*)yr;
    const f32x4* ys4 = (const f32x4*)ys;
    for (int i = threadIdx.x; i < n4; i += 256) {
        f32x4 a = yr4[i];
        f32x4 c = ys4[i];
        f32x4 d = a - c;
        s += d.x*d.x + d.y*d.y + d.z*d.z + d.w*d.w;
    }
    for (int i = (n4 << 2) + threadIdx.x; i < S; i += 256) {
        float d = yr[i] - ys[i];
        s += d * d;
    }
    u += s * c_mse;

    #pragma unroll
    for (int off = 32; off > 0; off >>= 1) u += __shfl_down(u, off, 64);
    __shared__ float wsum[4];
    int lane = threadIdx.x & 63, w = threadIdx.x >> 6;
    if (lane == 0) wsum[w] = u;
    __syncthreads();
    if (threadIdx.x == 0) out[b] = wsum[0] + wsum[1] + wsum[2] + wsum[3];
}

static void launch_fallback(const float* pred, const float* sigma,
                            const float* yReal, const float* ySim,
                            float* ws, float* out, int B, int S,
                            float c_mse, float c_prior, hipStream_t stream) {
    int pb = (B + 255) / 256;
    if (pb > 256) pb = 256;
    prior_partials<<<pb, 256, 0, stream>>>(pred, sigma, ws, B, pb);
    loss_kernel_g<<<B, 256, 0, stream>>>(yReal, ySim, ws, out, S, c_mse, c_prior, pb);
}

extern "C" void kernel_launch(void* const* d_in, const int* in_sizes, int n_in,
                              void* d_out, int out_size, void* d_ws, size_t ws_size,
                              hipStream_t stream) {
    const float* pred  = (const float*)d_in[0];
    const float* sigma = (const float*)d_in[1];
    const float* yReal = (const float*)d_in[2];
    const float* ySim  = (const float*)d_in[3];
    float* out = (float*)d_out;
    float* ws  = (float*)d_ws;

    int B = in_sizes[0] / 7;
    int S = in_sizes[2] / B;

    float c_mse   = 50.0f / (float)S;   // (1/S)*(1/(2*0.1^2))
    float c_prior = 1.0f / (float)B;

    if (S == 4096 || S == 2048) {
        // size the cooperative grid to guaranteed co-residency
        int dev = 0;
        hipGetDevice(&dev);
        int numCU = 0;
        hipDeviceGetAttribute(&numCU, hipDeviceAttributeMultiprocessorCount, dev);
        int occ = 0;
        if (S == 4096)
            hipOccupancyMaxActiveBlocksPerMultiprocessor(&occ, fused_loss<4>, 256, 0);
        else
            hipOccupancyMaxActiveBlocksPerMultiprocessor(&occ, fused_loss<2>, 256, 0);
        long nb_l = (long)occ * (long)numCU;
        if (nb_l > B) nb_l = B;
        int nb = (int)nb_l;

        // need ceil(B/nb) <= 32 for the LDS row buffer
        if (nb > 0 && (B + nb - 1) / nb <= 32) {
            void* args[] = {(void*)&pred, (void*)&sigma, (void*)&yReal, (void*)&ySim,
                            (void*)&ws, (void*)&out, (void*)&B, (void*)&S,
                            (void*)&c_mse, (void*)&c_prior, (void*)&nb};
            hipError_t e;
            if (S == 4096)
                e = hipLaunchCooperativeKernel(fused_loss<4>, dim3(nb), dim3(256),
                                               args, 0, stream);
            else
                e = hipLaunchCooperativeKernel(fused_loss<2>, dim3(nb), dim3(256),
                                               args, 0, stream);
            if (e == hipSuccess) return;
            // else fall through to the proven two-kernel path
        }
    }

    launch_fallback(pred, sigma, yReal, ySim, ws, out, B, S, c_mse, c_prior, stream);
}

// Round 6
// 47.638 us; speedup vs baseline: 3.6669x; 3.6669x over previous
//
#include <hip/hip_runtime.h>
#include <math.h>

#define LOG_SQRT_2PI 0.9189385332046727f
typedef float f32x4 __attribute__((ext_vector_type(4)));

// ---------------------------------------------------------------------------
// Per-row prior NLL (branchy expected-mu + 7-element gaussian NLL sum).
// ---------------------------------------------------------------------------
__device__ __forceinline__ float prior_row(const float* __restrict__ pred,
                                           const float* __restrict__ sigma,
                                           int b) {
    const float* p  = pred  + (size_t)b * 7;
    const float* sg = sigma + (size_t)b * 7;
    float O2 = p[0], N2 = p[1], H2 = p[2], CO2 = p[3];
    float H2O = p[4], CH4 = p[5], NH3 = p[6];

    float H = 2.f*H2 + 2.f*H2O + 3.f*NH3 + 4.f*CH4;
    float C = CO2 + CH4;
    float O = 2.f*O2 + 2.f*CO2 + H2O;
    float N = 2.f*N2 + NH3;

    float mu0=0.f, mu1=0.f, mu2=0.f, mu3=0.f, mu4=0.f, mu5=0.f, mu6=0.f;

    bool condA = (H > 2.f*O + 4.f*C);
    if (condA) {
        if (3.f*N < H - 2.f*O - 4.f*C) {
            float D = H - N - 2.f*C;                 // branch A1
            mu2 = (H - 2.f*O - 4.f*C - 3.f*N) / D;
            mu4 = (2.f*O) / D;
            mu5 = (2.f*C) / D;
            mu6 = (2.f*N) / D;
        } else {
            float D = H + 2.f*C + 3.f*N + 4.f*O;    // branch A2
            mu1 = (3.f*N + 4.f*C + 2.f*O - H) / D;
            mu4 = (6.f*O) / D;
            mu5 = (6.f*C) / D;
            mu6 = (2.f*H - 8.f*C - 4.f*O) / D;
        }
    } else if (2.f*O > H + 4.f*C) {
        float D = H + 2.f*O + 2.f*N;                // branch B
        mu0 = (2.f*O - H - 4.f*C) / D;
        mu1 = (2.f*N) / D;
        mu3 = (4.f*C) / D;
        mu4 = (2.f*H) / D;
    } else if (fabsf(H + C + O + N - 1.0f) < 1e-3f) {
        float D1 = H + 2.f*O + 2.f*N;               // branch C
        float D2 = 2.f*H + 4.f*O + 4.f*N;
        mu1 = (2.f*N) / D1;
        mu3 = (2.f*O + 4.f*C - H) / D2;
        mu4 = (H + 2.f*O - 4.f*C) / D1;
        mu5 = (H - 2.f*O + 4.f*C) / D2;
    }

    float mu[7] = {mu0, mu1, mu2, mu3, mu4, mu5, mu6};
    float s = 0.f;
    #pragma unroll
    for (int i = 0; i < 7; ++i) {
        float d = p[i] - mu[i];
        float sgi = sg[i];
        s += LOG_SQRT_2PI + logf(sgi) + d * d / (2.0f * sgi * sgi);
    }
    return s;
}

// ---------------------------------------------------------------------------
// Prior partials: pb blocks x 64 threads, one wave per block -> pure shfl
// reduce, no LDS, no __syncthreads. 128 blocks spreads the work over 128 CUs
// (vs 32 before) to shorten the serial prefix ahead of the streamer.
// ---------------------------------------------------------------------------
__global__ __launch_bounds__(64) void prior_partials(
        const float* __restrict__ pred,
        const float* __restrict__ sigma,
        float* __restrict__ ws, int B, int pb) {
    float s = 0.0f;
    for (int b = blockIdx.x * 64 + threadIdx.x; b < B; b += pb * 64)
        s += prior_row(pred, sigma, b);
    #pragma unroll
    for (int off = 32; off > 0; off >>= 1) s += __shfl_down(s, off, 64);
    if (threadIdx.x == 0) ws[blockIdx.x] = s;
}

// ---------------------------------------------------------------------------
// Loss: one 256-thread block per row (round-2 proven structure). Prior
// partials (<=256 floats, L2-hot) folded into the same block reduce.
// ---------------------------------------------------------------------------
template <int NITER>
__global__ __launch_bounds__(256) void loss_kernel_t(
        const float* __restrict__ yReal,
        const float* __restrict__ ySim,
        const float* __restrict__ partials,
        float* __restrict__ out, int S, float c_mse, float c_prior, int pb) {
    int b = blockIdx.x;
    const f32x4* yr = (const f32x4*)(yReal + (size_t)b * S);
    const f32x4* ys = (const f32x4*)(ySim  + (size_t)b * S);

    float u = (threadIdx.x < pb) ? partials[threadIdx.x] * c_prior : 0.0f;

    float s = 0.0f;
    #pragma unroll
    for (int k = 0; k < NITER; ++k) {
        int i = threadIdx.x + k * 256;
        f32x4 a = yr[i];
        f32x4 c = ys[i];
        f32x4 d = a - c;
        s += d.x*d.x + d.y*d.y + d.z*d.z + d.w*d.w;
    }
    u += s * c_mse;

    #pragma unroll
    for (int off = 32; off > 0; off >>= 1) u += __shfl_down(u, off, 64);
    __shared__ float wsum[4];
    int lane = threadIdx.x & 63, w = threadIdx.x >> 6;
    if (lane == 0) wsum[w] = u;
    __syncthreads();
    if (threadIdx.x == 0) out[b] = wsum[0] + wsum[1] + wsum[2] + wsum[3];
}

// generic fallback (runtime trip count)
__global__ __launch_bounds__(256) void loss_kernel_g(
        const float* __restrict__ yReal,
        const float* __restrict__ ySim,
        const float* __restrict__ partials,
        float* __restrict__ out, int S, float c_mse, float c_prior, int pb) {
    int b = blockIdx.x;
    const float* yr = yReal + (size_t)b * S;
    const float* ys = ySim  + (size_t)b * S;

    float u = (threadIdx.x < pb) ? partials[threadIdx.x] * c_prior : 0.0f;

    float s = 0.0f;
    int n4 = S >> 2;
    const f32x4* yr4 = (const f32x4*)yr;
    const f32x4* ys4 = (const f32x4*)ys;
    for (int i = threadIdx.x; i < n4; i += 256) {
        f32x4 a = yr4[i];
        f32x4 c = ys4[i];
        f32x4 d = a - c;
        s += d.x*d.x + d.y*d.y + d.z*d.z + d.w*d.w;
    }
    for (int i = (n4 << 2) + threadIdx.x; i < S; i += 256) {
        float d = yr[i] - ys[i];
        s += d * d;
    }
    u += s * c_mse;

    #pragma unroll
    for (int off = 32; off > 0; off >>= 1) u += __shfl_down(u, off, 64);
    __shared__ float wsum[4];
    int lane = threadIdx.x & 63, w = threadIdx.x >> 6;
    if (lane == 0) wsum[w] = u;
    __syncthreads();
    if (threadIdx.x == 0) out[b] = wsum[0] + wsum[1] + wsum[2] + wsum[3];
}

extern "C" void kernel_launch(void* const* d_in, const int* in_sizes, int n_in,
                              void* d_out, int out_size, void* d_ws, size_t ws_size,
                              hipStream_t stream) {
    const float* pred  = (const float*)d_in[0];
    const float* sigma = (const float*)d_in[1];
    const float* yReal = (const float*)d_in[2];
    const float* ySim  = (const float*)d_in[3];
    float* out = (float*)d_out;
    float* ws  = (float*)d_ws;

    int B = in_sizes[0] / 7;
    int S = in_sizes[2] / B;

    // 64-thread blocks, 1 row/thread where possible; cap partial count at 256
    // (the loss kernel folds partials via tid<pb with 256 threads).
    int pb = (B + 63) / 64;
    if (pb > 256) pb = 256;

    prior_partials<<<pb, 64, 0, stream>>>(pred, sigma, ws, B, pb);

    float c_mse   = 50.0f / (float)S;   // (1/S)*(1/(2*0.1^2))
    float c_prior = 1.0f / (float)B;

    if (S == 4096) {
        loss_kernel_t<4><<<B, 256, 0, stream>>>(yReal, ySim, ws, out, S, c_mse, c_prior, pb);
    } else if (S == 2048) {
        loss_kernel_t<2><<<B, 256, 0, stream>>>(yReal, ySim, ws, out, S, c_mse, c_prior, pb);
    } else {
        loss_kernel_g<<<B, 256, 0, stream>>>(yReal, ySim, ws, out, S, c_mse, c_prior, pb);
    }
}